// Round 8
// baseline (319.658 us; speedup 1.0000x reference)
//
#include <hip/hip_runtime.h>
#include <hip/hip_fp16.h>

#define N_NODES   100000
#define N_EDGES   3200000
#define IN_CH     128
#define NUM_GRAPHS 1000
#define NHALF     50000    // src-half boundary
#define NBH       391      // dst-buckets per src-half (256 nodes each)
#define NB2       782      // total buckets = 2 src-halves x 391
#define PAIR_CAP  4608     // per-bucket raw capacity (mean 4096, +8 sigma)
#define CSR_CAP   6912     // per-bucket padded capacity (rows padded to 16; mean ~5900)
#define CHUNK     4096     // edges per block in the binning pass
#define NBLK_BIN  782      // ceil(3200000/4096)
#define RPW       257      // rowptr words per bucket (256 nodes + legacy pad)
#define NTILE     6250     // N_NODES / 16  (16-node tiles, MFMA + gather32f)
#define NBLK_G16  3125     // N_NODES * 8 / 256 (merged-hh 16-ch gather)
#define NBLK_G32  (1563 * 8)   // ceil(NTILE/4)*8 (R3-proven gather32f grid)

typedef __attribute__((ext_vector_type(8))) _Float16 half8;
typedef __attribute__((ext_vector_type(4))) float    float4v;
typedef __attribute__((ext_vector_type(4))) int      intx4;
typedef __attribute__((ext_vector_type(2))) float    floatx2;

// ---------------------------------------------------------------------------
// Gather helpers (proven). csr is sentinel-padded (index N_NODES -> zeroed
// table row), so the inner loops have no masking.
// ---------------------------------------------------------------------------
__device__ __forceinline__ void ld16(const int* __restrict__ p, int* sv) {
    *(intx4*)(sv)      = __builtin_nontemporal_load((const intx4*)(p));
    *(intx4*)(sv + 4)  = __builtin_nontemporal_load((const intx4*)(p + 4));
    *(intx4*)(sv + 8)  = __builtin_nontemporal_load((const intx4*)(p + 8));
    *(intx4*)(sv + 12) = __builtin_nontemporal_load((const intx4*)(p + 12));
}

template <int STRIDE>
__device__ __forceinline__ void acc16(const unsigned* __restrict__ tb,
                                      const int* sv, floatx2* ac) {
#pragma unroll
    for (int k = 0; k < 16; ++k) {
        unsigned hv = tb[(unsigned)sv[k] * (unsigned)STRIDE];
        float2 f = __half22float2(__builtin_bit_cast(__half2, hv));
        ac[k & 3] += __builtin_bit_cast(floatx2, f);
    }
}

// ---------------------------------------------------------------------------
// Scatter: LDS counting sort per 4096-edge chunk (proven, untouched).
// ---------------------------------------------------------------------------
__global__ __launch_bounds__(1024, 2) void k_scatter_pairs(
    const int* __restrict__ ei, int* __restrict__ cursor,
    int* __restrict__ pairbuf)
{
    __shared__ int h[NB2];
    __shared__ int gbase[NB2];
    __shared__ int sstart[NB2 + 1];
    __shared__ int sa[1024];
    __shared__ int sb[1024];
    __shared__ int ebuf[CHUNK];
    __shared__ unsigned short sbk[CHUNK];
    int tid = threadIdx.x;
    if (tid < NB2) h[tid] = 0;
    __syncthreads();
    int base = blockIdx.x * CHUNK;
    int end = min(base + CHUNK, N_EDGES);
    int cntE = end - base;
    int eb[4], ep[4];
#pragma unroll
    for (int r = 0; r < 4; ++r) {
        int e = base + tid + 1024 * r;
        eb[r] = -1;
        if (e < end) {
            int src = ei[e];
            int dst = ei[N_EDGES + e];
            int bk = ((src >= NHALF) ? NBH : 0) + (dst >> 8);
            eb[r] = bk;
            ep[r] = src | ((dst & 255) << 17);
            atomicAdd(&h[bk], 1);
        }
    }
    __syncthreads();
    sa[tid] = (tid < NB2) ? h[tid] : 0;
    __syncthreads();
    int* A = sa; int* B = sb;
    for (int off = 1; off < 1024; off <<= 1) {
        int v = A[tid] + ((tid >= off) ? A[tid - off] : 0);
        __syncthreads();
        B[tid] = v;
        __syncthreads();
        int* tmp = A; A = B; B = tmp;
    }
    if (tid == 0) sstart[0] = 0;
    if (tid < NB2) sstart[tid + 1] = A[tid];
    __syncthreads();
    if (tid < NB2) {
        int c = sstart[tid + 1] - sstart[tid];
        gbase[tid] = c ? (tid * PAIR_CAP + atomicAdd(&cursor[tid], c)) : 0;
        h[tid] = 0;
    }
    __syncthreads();
#pragma unroll
    for (int r = 0; r < 4; ++r) {
        if (eb[r] >= 0) {
            int off = atomicAdd(&h[eb[r]], 1);
            int slot = sstart[eb[r]] + off;
            ebuf[slot] = ep[r];
            sbk[slot] = (unsigned short)eb[r];
        }
    }
    __syncthreads();
#pragma unroll
    for (int r = 0; r < 4; ++r) {
        int i = tid + 1024 * r;
        if (i < cntE) {
            int bk = sbk[i];
            pairbuf[gbase[bk] + (i - sstart[bk])] = ebuf[i];
        }
    }
}

// ---------------------------------------------------------------------------
// Build CSR (proven, untouched): rows padded to multiples of 16 with sentinel
// index N_NODES; LDS-staged coalesced output.
// ---------------------------------------------------------------------------
__global__ __launch_bounds__(1024, 2) void k_build_csr(const int* __restrict__ cursor,
                                                       const int* __restrict__ pairbuf,
                                                       int* __restrict__ rowptr,
                                                       int* __restrict__ csr)
{
    __shared__ int cnt[256];
    __shared__ int scanv[256];
    __shared__ int ebuf[PAIR_CAP];
    __shared__ int obuf[CSR_CAP];
    int b = blockIdx.x;
    int base = b * CSR_CAP;
    int pbase = b * PAIR_CAP;
    int cntE = cursor[b];
    int tid = threadIdx.x;
    if (tid < 256) cnt[tid] = 0;
    __syncthreads();
    for (int i = tid; i < cntE; i += 1024) {
        int p = __builtin_nontemporal_load(&pairbuf[pbase + i]);
        ebuf[i] = p;
        atomicAdd(&cnt[(p >> 17) & 255], 1);
    }
    __syncthreads();
    int v = 0, vr = 0;
    if (tid < 256) { v = cnt[tid]; vr = (v + 15) & ~15; scanv[tid] = vr; }
    __syncthreads();
    for (int off = 1; off < 256; off <<= 1) {
        int t = (tid < 256 && tid >= off) ? scanv[tid - off] : 0;
        __syncthreads();
        if (tid < 256) scanv[tid] += t;
        __syncthreads();
    }
    int ex = 0;
    if (tid < 256) {
        ex = scanv[tid] - vr;              // exclusive scan of padded counts
        rowptr[b * RPW + tid] = (unsigned)((base + ex) >> 4) | ((unsigned)(vr >> 4) << 20);
        cnt[tid] = ex;
    }
    __syncthreads();
    int pt = scanv[255];                   // padded total (multiple of 16)
    for (int i = tid; i < pt; i += 1024) obuf[i] = N_NODES;
    __syncthreads();
    for (int i = tid; i < cntE; i += 1024) {
        int p = ebuf[i];
        int pos = atomicAdd(&cnt[(p >> 17) & 255], 1);
        obuf[pos] = p & 0x1FFFF;
    }
    __syncthreads();
    for (int i = tid * 4; i < pt; i += 4096) {
        intx4 vv = *(const intx4*)(obuf + i);
        *(intx4*)(csr + base + i) = vv;
    }
}

// ---------------------------------------------------------------------------
// Graph boundaries from sorted batch: gstart[g] = first node of graph g.
// ---------------------------------------------------------------------------
__global__ __launch_bounds__(256) void k_gstart(const int* __restrict__ batch,
                                                int* __restrict__ gstart)
{
    int n = blockIdx.x * 256 + threadIdx.x;
    if (n >= N_NODES) return;
    int cur = batch[n];
    int prev = (n == 0) ? -1 : batch[n - 1];
    for (int g = prev + 1; g <= cur; ++g) gstart[g] = n;
    if (n == N_NODES - 1)
        for (int g = cur + 1; g <= NUM_GRAPHS; ++g) gstart[g] = N_NODES;
}

// ---------------------------------------------------------------------------
// transform1 via MFMA f16 (proven, untouched): t1 = half(x @ W1_nbr);
// r1 = x @ W1_root + b1. Also zeroes sentinel row N_NODES of t1.
// ---------------------------------------------------------------------------
__global__ __launch_bounds__(256) void k_transform1_mfma(
    const float* __restrict__ x,
    const float* __restrict__ W1n, const float* __restrict__ W1r,
    const float* __restrict__ b1,
    __half* __restrict__ t1, float* __restrict__ r1)
{
    if (blockIdx.x == 0 && threadIdx.x < 16)
        ((unsigned short*)t1)[N_NODES * 16 + threadIdx.x] = 0;
    int wave = threadIdx.x >> 6;
    int lane = threadIdx.x & 63;
    int tile = blockIdx.x * 4 + wave;
    int node0 = tile * 16;
    int m = lane & 15, quad = lane >> 4;
    int row = node0 + m;
    if (row >= N_NODES) row = N_NODES - 1;
    const float* xr = x + (size_t)row * IN_CH + quad * 8;

    float4v acc_n = {0.f, 0.f, 0.f, 0.f};
    float4v acc_r = {0.f, 0.f, 0.f, 0.f};
#pragma unroll
    for (int kc = 0; kc < 4; ++kc) {
        half8 a, bn, br;
        const float* xp = xr + kc * 32;
#pragma unroll
        for (int j = 0; j < 8; ++j) a[j] = (_Float16)xp[j];
        int kbase = kc * 32 + quad * 8;
#pragma unroll
        for (int j = 0; j < 8; ++j) {
            bn[j] = (_Float16)W1n[(kbase + j) * 16 + m];
            br[j] = (_Float16)W1r[(kbase + j) * 16 + m];
        }
        acc_n = __builtin_amdgcn_mfma_f32_16x16x32_f16(a, bn, acc_n, 0, 0, 0);
        acc_r = __builtin_amdgcn_mfma_f32_16x16x32_f16(a, br, acc_r, 0, 0, 0);
    }
    float bias = b1[m];
#pragma unroll
    for (int reg = 0; reg < 4; ++reg) {
        int node = node0 + quad * 4 + reg;
        if (node < N_NODES) {
            t1[node * 16 + m] = __float2half_rn(acc_n[reg]);
            r1[node * 16 + m] = acc_r[reg] + bias;
        }
    }
}

// ---------------------------------------------------------------------------
// 16-channel gather, merged halves (R1-proven hh-loop + R6-proven sentinel
// inner loop): 8 lanes/node, 32 nodes/block, both src-halves accumulated in
// one pass (table 3.2 MB fits any XCD L2 whole), SINGLE agg output.
// ---------------------------------------------------------------------------
__global__ __launch_bounds__(256, 8) void k_gather16b(
    const int* __restrict__ rowptr, const int* __restrict__ csr,
    const unsigned* __restrict__ t,
    float* __restrict__ agg)
{
    int n = blockIdx.x * 32 + (threadIdx.x >> 3);
    int cp = threadIdx.x & 7;
    const unsigned* tb = t + cp;
    floatx2 ac[4];
#pragma unroll
    for (int i = 0; i < 4; ++i) ac[i] = (floatx2){0.f, 0.f};
#pragma unroll
    for (int hh = 0; hh < 2; ++hh) {
        unsigned w = ((const unsigned*)rowptr)[(hh * NBH + (n >> 8)) * RPW + (n & 255)];
        int j = (int)(w & 0xFFFFFu) << 4;
        int end = j + ((int)(w >> 20) << 4);
        if (j < end) {
            int sv[16] __attribute__((aligned(16)));
            ld16(csr + j, sv);
            j += 16;
            while (j < end) {
                int sw[16] __attribute__((aligned(16)));
                ld16(csr + j, sw);
                j += 16;
                acc16<8>(tb, sv, ac);
#pragma unroll
                for (int k = 0; k < 16; ++k) sv[k] = sw[k];
            }
            acc16<8>(tb, sv, ac);
        }
    }
    float rx = (ac[0].x + ac[1].x) + (ac[2].x + ac[3].x);
    float ry = (ac[0].y + ac[1].y) + (ac[2].y + ac[3].y);
    __builtin_nontemporal_store(rx, &agg[n * 16 + 2 * cp]);
    __builtin_nontemporal_store(ry, &agg[n * 16 + 2 * cp + 1]);
}

// ---------------------------------------------------------------------------
// 32-channel gather (R3-proven form, 41us measured): 16 lanes/node scalar
// dword, 16 nodes/block-tile, XCD-partitioned halves, pipelined sentinel
// batches. Two agg outputs (h2 6.4MB > 4MB/XCD so half-split pays here).
// ---------------------------------------------------------------------------
__global__ __launch_bounds__(256, 8) void k_gather32f(
    const int* __restrict__ rowptr, const int* __restrict__ csr,
    const unsigned* __restrict__ t,
    float* __restrict__ aggA, float* __restrict__ aggB)
{
    int b = blockIdx.x;
    int half = (b >> 2) & 1;
    int tile = (b >> 3) * 4 + (b & 3);
    if (tile >= NTILE) return;
    int n = tile * 16 + (threadIdx.x >> 4);
    int cp = threadIdx.x & 15;
    float* agg = half ? aggB : aggA;
    unsigned w = ((const unsigned*)rowptr)[(half * NBH + (n >> 8)) * RPW + (n & 255)];
    int j = (int)(w & 0xFFFFFu) << 4;
    int end = j + ((int)(w >> 20) << 4);
    const unsigned* tb = t + cp;
    floatx2 ac[4];
#pragma unroll
    for (int i = 0; i < 4; ++i) ac[i] = (floatx2){0.f, 0.f};
    if (j < end) {
        int sv[16] __attribute__((aligned(16)));
        ld16(csr + j, sv);
        j += 16;
        while (j < end) {
            int sw[16] __attribute__((aligned(16)));
            ld16(csr + j, sw);
            j += 16;
            acc16<16>(tb, sv, ac);
#pragma unroll
            for (int k = 0; k < 16; ++k) sv[k] = sw[k];
        }
        acc16<16>(tb, sv, ac);
    }
    float rx = (ac[0].x + ac[1].x) + (ac[2].x + ac[3].x);
    float ry = (ac[0].y + ac[1].y) + (ac[2].y + ac[3].y);
    __builtin_nontemporal_store(rx, &agg[n * 32 + 2 * cp]);
    __builtin_nontemporal_store(ry, &agg[n * 32 + 2 * cp + 1]);
}

// ---------------------------------------------------------------------------
// combine1 (elementwise): h1 = f16(relu(r1 + agg)). Zeroes sentinel row.
// ---------------------------------------------------------------------------
__global__ __launch_bounds__(256) void k_combine1_relu(
    const float* __restrict__ r1,
    const float* __restrict__ agg,
    __half* __restrict__ h1)
{
    if (blockIdx.x == 0 && threadIdx.x < 16)
        h1[(size_t)N_NODES * 16 + threadIdx.x] = __float2half_rn(0.f);
    int i = (blockIdx.x * 256 + threadIdx.x) * 4;
    if (i >= N_NODES * 16) return;
    float4v a = *(const float4v*)(r1 + i);
    float4v b = *(const float4v*)(agg + i);
    float v0 = a[0] + b[0]; v0 = v0 > 0.f ? v0 : 0.f;
    float v1 = a[1] + b[1]; v1 = v1 > 0.f ? v1 : 0.f;
    float v2 = a[2] + b[2]; v2 = v2 > 0.f ? v2 : 0.f;
    float v3 = a[3] + b[3]; v3 = v3 > 0.f ? v3 : 0.f;
    __half2* dst = (__half2*)(h1 + i);
    dst[0] = __floats2half2_rn(v0, v1);
    dst[1] = __floats2half2_rn(v2, v3);
}

// ---------------------------------------------------------------------------
// combine2: h2 = relu([h1 | agg_h1] @ [W2r; W2n] + b2), K=32 concat MFMA.
// A: quad<2 -> h1 f16 direct; quad>=2 -> f16(agg). Zeroes sentinel row.
// ---------------------------------------------------------------------------
__global__ __launch_bounds__(256) void k_combine2_mfma(
    const __half* __restrict__ h1,
    const float* __restrict__ agg,
    const float* __restrict__ W2r, const float* __restrict__ W2n,
    const float* __restrict__ b2,
    __half* __restrict__ h2)
{
    if (blockIdx.x == 0 && threadIdx.x < 32)
        h2[(size_t)N_NODES * 32 + threadIdx.x] = __float2half_rn(0.f);
    int wave = threadIdx.x >> 6;
    int lane = threadIdx.x & 63;
    int tile = blockIdx.x * 4 + wave;
    if (tile >= NTILE) return;
    int node0 = tile * 16;
    int m = lane & 15, quad = lane >> 4;

    half8 bf[2];
#pragma unroll
    for (int g = 0; g < 2; ++g) {
#pragma unroll
        for (int j = 0; j < 8; ++j) {
            int k = quad * 8 + j;
            int c = g * 16 + m;
            float w = (k < 16) ? W2r[k * 32 + c] : W2n[(k - 16) * 32 + c];
            bf[g][j] = (_Float16)w;
        }
    }

    half8 a;
    if (quad < 2) {
        a = *(const half8*)(h1 + (node0 + m) * 16 + quad * 8);
    } else {
        int idx = (node0 + m) * 16 + (quad - 2) * 8;
#pragma unroll
        for (int j = 0; j < 8; ++j)
            a[j] = (_Float16)agg[idx + j];
    }

    float4v acc0 = {0,0,0,0}, acc1 = {0,0,0,0};
    acc0 = __builtin_amdgcn_mfma_f32_16x16x32_f16(a, bf[0], acc0, 0, 0, 0);
    acc1 = __builtin_amdgcn_mfma_f32_16x16x32_f16(a, bf[1], acc1, 0, 0, 0);

    float bias0 = b2[m], bias1 = b2[16 + m];
#pragma unroll
    for (int reg = 0; reg < 4; ++reg) {
        int node = node0 + quad * 4 + reg;
        float v0 = acc0[reg] + bias0; v0 = v0 > 0.f ? v0 : 0.f;
        float v1 = acc1[reg] + bias1; v1 = v1 > 0.f ? v1 : 0.f;
        h2[node * 32 + m]      = __float2half_rn(v0);
        h2[node * 32 + 16 + m] = __float2half_rn(v1);
    }
}

// ---------------------------------------------------------------------------
// combine3: h3 = relu([h2 | aggA+aggB] @ [W3r; W3n] + b3), K=64 via two
// chained K=32 MFMAs. Output h3 fp32 (the only stream pool reads).
// ---------------------------------------------------------------------------
__global__ __launch_bounds__(256) void k_combine3_mfma(
    const __half* __restrict__ h2,
    const float* __restrict__ aggA, const float* __restrict__ aggB,
    const float* __restrict__ W3r, const float* __restrict__ W3n,
    const float* __restrict__ b3,
    float* __restrict__ h3)
{
    int wave = threadIdx.x >> 6;
    int lane = threadIdx.x & 63;
    int tile = blockIdx.x * 4 + wave;
    if (tile >= NTILE) return;
    int node0 = tile * 16;
    int m = lane & 15, quad = lane >> 4;

    half8 bfl[2], bfh[2];
#pragma unroll
    for (int g = 0; g < 2; ++g) {
#pragma unroll
        for (int j = 0; j < 8; ++j) {
            int k = quad * 8 + j;
            int c = g * 16 + m;
            bfl[g][j] = (_Float16)W3r[k * 32 + c];
            bfh[g][j] = (_Float16)W3n[k * 32 + c];
        }
    }

    int idx = (node0 + m) * 32 + quad * 8;
    half8 al = *(const half8*)(h2 + idx);
    half8 ah;
#pragma unroll
    for (int j = 0; j < 8; ++j)
        ah[j] = (_Float16)(aggA[idx + j] + aggB[idx + j]);

    float4v acc0 = {0,0,0,0}, acc1 = {0,0,0,0};
    acc0 = __builtin_amdgcn_mfma_f32_16x16x32_f16(al, bfl[0], acc0, 0, 0, 0);
    acc0 = __builtin_amdgcn_mfma_f32_16x16x32_f16(ah, bfh[0], acc0, 0, 0, 0);
    acc1 = __builtin_amdgcn_mfma_f32_16x16x32_f16(al, bfl[1], acc1, 0, 0, 0);
    acc1 = __builtin_amdgcn_mfma_f32_16x16x32_f16(ah, bfh[1], acc1, 0, 0, 0);

    float bias0 = b3[m], bias1 = b3[16 + m];
#pragma unroll
    for (int reg = 0; reg < 4; ++reg) {
        int node = node0 + quad * 4 + reg;
        float v0 = acc0[reg] + bias0; v0 = v0 > 0.f ? v0 : 0.f;
        float v1 = acc1[reg] + bias1; v1 = v1 > 0.f ? v1 : 0.f;
        h3[node * 32 + m]      = v0;
        h3[node * 32 + 16 + m] = v1;
    }
}

// ---------------------------------------------------------------------------
// Fused pool + final: pooled = sum_graph h3; out = pooled @ Wlin + blin.
// ---------------------------------------------------------------------------
__global__ __launch_bounds__(256) void k_pool_final(
    const float* __restrict__ h3,
    const int* __restrict__ gstart,
    const float* __restrict__ Wlin, const float* __restrict__ blin,
    float* __restrict__ out)
{
    __shared__ float part[8][32];
    __shared__ float pooled[32];
    int g = blockIdx.x;
    int s = gstart[g], e = gstart[g + 1];
    int nl = threadIdx.x >> 5, c = threadIdx.x & 31;
    float acc = 0.f;
    for (int n = s + nl; n < e; n += 8)
        acc += h3[n * 32 + c];
    part[nl][c] = acc;
    __syncthreads();
    if (threadIdx.x < 32) {
        float s2 = 0.f;
#pragma unroll
        for (int i = 0; i < 8; ++i) s2 += part[i][threadIdx.x];
        pooled[threadIdx.x] = s2;
    }
    __syncthreads();
    if (threadIdx.x < 64) {
        int o = threadIdx.x;
        float a = blin[o];
#pragma unroll
        for (int k = 0; k < 32; ++k) a += pooled[k] * Wlin[k * 64 + o];
        out[g * 64 + o] = a;
    }
}

static inline char* align16p(char* p) {
    return (char*)(((uintptr_t)p + 15) & ~(uintptr_t)15);
}

extern "C" void kernel_launch(void* const* d_in, const int* in_sizes, int n_in,
                              void* d_out, int out_size, void* d_ws, size_t ws_size,
                              hipStream_t stream) {
    const float* x     = (const float*)d_in[0];
    const int*   ei    = (const int*)d_in[1];
    const int*   batch = (const int*)d_in[2];
    const float* W1r   = (const float*)d_in[3];
    const float* W1n   = (const float*)d_in[4];
    const float* b1    = (const float*)d_in[5];
    const float* W2r   = (const float*)d_in[6];
    const float* W2n   = (const float*)d_in[7];
    const float* b2    = (const float*)d_in[8];
    const float* W3r   = (const float*)d_in[9];
    const float* W3n   = (const float*)d_in[10];
    const float* b3    = (const float*)d_in[11];
    const float* Wlin  = (const float*)d_in[12];
    const float* blin  = (const float*)d_in[13];
    float* out = (float*)d_out;

    // ---- workspace layout --------------------------------------------------
    // cursor | gstart | rowptr 0.80MB | csr 21.6MB |
    // pairbuf 14.4MB { t1 3.2 + r1 6.4 during layer1; agg3B 12.8 for layer3 } |
    // agg16 6.4 + 6.4 spare (contiguous 12.8; reused as agg3A for layer3) |
    // h1 3.2 | h2 6.4 | h3 12.8.   total ~72 MB.
    char* p = (char*)d_ws;
    int*   cursor = (int*)p;               p += 1024 * 4;
    int*   gstart = (int*)p;               p += 1024 * 4;
    int*   rowptr = (int*)p;               p += (size_t)NB2 * RPW * 4;
    p = align16p(p);
    int*   csr    = (int*)p;               p += (size_t)NB2 * CSR_CAP * 4;
    p = align16p(p);
    int*   pairbuf= (int*)p;
    __half* t1    = (__half*)pairbuf;                                   // alias
    float*  r1    = (float*)((char*)pairbuf + (size_t)(N_NODES + 1) * 16 * 2);
    float*  agg3B = (float*)pairbuf;       // alias, live for layer-3 only
    p += (size_t)NB2 * PAIR_CAP * 4;
    p = align16p(p);
    float*  agg16 = (float*)p;             p += (size_t)N_NODES * 16 * 4 * 2; // 12.8 contiguous
    float*  agg3A = agg16;                 // reused for layer-3 (12.8)
    __half* h1    = (__half*)p;            p += (size_t)(N_NODES + 1) * 16 * 2;
    __half* h2    = (__half*)align16p(p);  p = (char*)h2 + (size_t)(N_NODES + 1) * 32 * 2;
    float*  h3    = (float*)align16p(p);

    hipMemsetAsync(cursor, 0, 1024 * 4, stream);

    // Bucketed CSR build + graph boundaries
    k_scatter_pairs<<<NBLK_BIN, 1024, 0, stream>>>(ei, cursor, pairbuf);
    k_build_csr    <<<NB2, 1024, 0, stream>>>(cursor, pairbuf, rowptr, csr);
    k_gstart       <<<(N_NODES + 255) / 256, 256, 0, stream>>>(batch, gstart);

    // Layer 1: transform-first (x is 128ch; t1 = x@W1n is 16ch)
    k_transform1_mfma<<<(NTILE + 3) / 4, 256, 0, stream>>>(x, W1n, W1r, b1, t1, r1);
    k_gather16b<<<NBLK_G16, 256, 0, stream>>>(rowptr, csr,
                    (const unsigned*)t1, agg16);
    k_combine1_relu<<<(N_NODES * 16 / 4 + 255) / 256, 256, 0, stream>>>(
                    r1, agg16, h1);

    // Layer 2: aggregate-first (gather 16ch h1, transform after aggregation)
    k_gather16b<<<NBLK_G16, 256, 0, stream>>>(rowptr, csr,
                    (const unsigned*)h1, agg16);
    k_combine2_mfma<<<(NTILE + 3) / 4, 256, 0, stream>>>(
                    h1, agg16, W2r, W2n, b2, h2);

    // Layer 3: aggregate-first (gather 32ch h2, half-split for XCD L2)
    k_gather32f<<<NBLK_G32, 256, 0, stream>>>(rowptr, csr,
                    (const unsigned*)h2, agg3A, agg3B);
    k_combine3_mfma<<<(NTILE + 3) / 4, 256, 0, stream>>>(
                    h2, agg3A, agg3B, W3r, W3n, b3, h3);

    // Pool + final linear
    k_pool_final<<<NUM_GRAPHS, 256, 0, stream>>>(h3, gstart, Wlin, blin, out);
}

// Round 9
// 294.366 us; speedup vs baseline: 1.0859x; 1.0859x over previous
//
#include <hip/hip_runtime.h>
#include <hip/hip_fp16.h>

#define N_NODES   100000
#define N_EDGES   3200000
#define IN_CH     128
#define NUM_GRAPHS 1000
#define NHALF     50000    // src-half boundary
#define NBH       391      // dst-buckets per src-half (256 nodes each)
#define NB2       782      // total buckets = 2 src-halves x 391
#define PAIR_CAP  4608     // per-bucket raw capacity (mean 4096, +8 sigma)
#define CSR_CAP   6912     // per-bucket padded capacity (rows padded to 16; mean ~5900)
#define CHUNK     4096     // edges per block in the binning pass
#define NBLK_BIN  782      // ceil(3200000/4096)
#define RPW       257      // rowptr words per bucket (256 nodes + legacy pad)
#define NTILE     6250     // N_NODES / 16  (16-node tiles, MFMA kernels)
#define NTILE32   3125     // N_NODES / 32  (32-node tiles, gather32f)
#define NBLK_G16  3125     // N_NODES*8/256 (merged-hh 16-ch gathers)
#define NBLK_G32  (((NTILE32 + 3) / 4) * 8)   // 6256 (R7-proven gather32f grid)

typedef __attribute__((ext_vector_type(8))) _Float16 half8;
typedef __attribute__((ext_vector_type(4))) float    float4v;
typedef __attribute__((ext_vector_type(4))) int      intx4;
typedef __attribute__((ext_vector_type(2))) float    floatx2;

// ---------------------------------------------------------------------------
// Gather helpers (proven). csr is sentinel-padded (index N_NODES -> zeroed
// table row), so the inner loops have no masking.
// ---------------------------------------------------------------------------
__device__ __forceinline__ void ld16(const int* __restrict__ p, int* sv) {
    *(intx4*)(sv)      = __builtin_nontemporal_load((const intx4*)(p));
    *(intx4*)(sv + 4)  = __builtin_nontemporal_load((const intx4*)(p + 4));
    *(intx4*)(sv + 8)  = __builtin_nontemporal_load((const intx4*)(p + 8));
    *(intx4*)(sv + 12) = __builtin_nontemporal_load((const intx4*)(p + 12));
}

template <int STRIDE>
__device__ __forceinline__ void acc16(const unsigned* __restrict__ tb,
                                      const int* sv, floatx2* ac) {
#pragma unroll
    for (int k = 0; k < 16; ++k) {
        unsigned hv = tb[(unsigned)sv[k] * (unsigned)STRIDE];
        float2 f = __half22float2(__builtin_bit_cast(__half2, hv));
        ac[k & 3] += __builtin_bit_cast(floatx2, f);
    }
}

__device__ __forceinline__ void acc16w(const uint2* __restrict__ tb,
                                       const int* sv, floatx2* ac, floatx2* bc) {
#pragma unroll
    for (int k = 0; k < 16; ++k) {
        uint2 hv = tb[(unsigned)sv[k] * 8u];
        float2 f0 = __half22float2(__builtin_bit_cast(__half2, hv.x));
        float2 f1 = __half22float2(__builtin_bit_cast(__half2, hv.y));
        ac[k & 3] += __builtin_bit_cast(floatx2, f0);
        bc[k & 3] += __builtin_bit_cast(floatx2, f1);
    }
}

// Shared 16-ch merged-hh gather core (R8-proven): accumulates both src-halves
// for node n, channel pair (2cp, 2cp+1) into (rx, ry).
__device__ __forceinline__ void gather16_core(
    const int* __restrict__ rowptr, const int* __restrict__ csr,
    const unsigned* __restrict__ t, int n, int cp, float& rx, float& ry)
{
    const unsigned* tb = t + cp;
    floatx2 ac[4];
#pragma unroll
    for (int i = 0; i < 4; ++i) ac[i] = (floatx2){0.f, 0.f};
#pragma unroll
    for (int hh = 0; hh < 2; ++hh) {
        unsigned w = ((const unsigned*)rowptr)[(hh * NBH + (n >> 8)) * RPW + (n & 255)];
        int j = (int)(w & 0xFFFFFu) << 4;
        int end = j + ((int)(w >> 20) << 4);
        if (j < end) {
            int sv[16] __attribute__((aligned(16)));
            ld16(csr + j, sv);
            j += 16;
            while (j < end) {
                int sw[16] __attribute__((aligned(16)));
                ld16(csr + j, sw);
                j += 16;
                acc16<8>(tb, sv, ac);
#pragma unroll
                for (int k = 0; k < 16; ++k) sv[k] = sw[k];
            }
            acc16<8>(tb, sv, ac);
        }
    }
    rx = (ac[0].x + ac[1].x) + (ac[2].x + ac[3].x);
    ry = (ac[0].y + ac[1].y) + (ac[2].y + ac[3].y);
}

// ---------------------------------------------------------------------------
// Scatter: LDS counting sort per 4096-edge chunk (proven, untouched).
// ---------------------------------------------------------------------------
__global__ __launch_bounds__(1024, 2) void k_scatter_pairs(
    const int* __restrict__ ei, int* __restrict__ cursor,
    int* __restrict__ pairbuf)
{
    __shared__ int h[NB2];
    __shared__ int gbase[NB2];
    __shared__ int sstart[NB2 + 1];
    __shared__ int sa[1024];
    __shared__ int sb[1024];
    __shared__ int ebuf[CHUNK];
    __shared__ unsigned short sbk[CHUNK];
    int tid = threadIdx.x;
    if (tid < NB2) h[tid] = 0;
    __syncthreads();
    int base = blockIdx.x * CHUNK;
    int end = min(base + CHUNK, N_EDGES);
    int cntE = end - base;
    int eb[4], ep[4];
#pragma unroll
    for (int r = 0; r < 4; ++r) {
        int e = base + tid + 1024 * r;
        eb[r] = -1;
        if (e < end) {
            int src = ei[e];
            int dst = ei[N_EDGES + e];
            int bk = ((src >= NHALF) ? NBH : 0) + (dst >> 8);
            eb[r] = bk;
            ep[r] = src | ((dst & 255) << 17);
            atomicAdd(&h[bk], 1);
        }
    }
    __syncthreads();
    sa[tid] = (tid < NB2) ? h[tid] : 0;
    __syncthreads();
    int* A = sa; int* B = sb;
    for (int off = 1; off < 1024; off <<= 1) {
        int v = A[tid] + ((tid >= off) ? A[tid - off] : 0);
        __syncthreads();
        B[tid] = v;
        __syncthreads();
        int* tmp = A; A = B; B = tmp;
    }
    if (tid == 0) sstart[0] = 0;
    if (tid < NB2) sstart[tid + 1] = A[tid];
    __syncthreads();
    if (tid < NB2) {
        int c = sstart[tid + 1] - sstart[tid];
        gbase[tid] = c ? (tid * PAIR_CAP + atomicAdd(&cursor[tid], c)) : 0;
        h[tid] = 0;
    }
    __syncthreads();
#pragma unroll
    for (int r = 0; r < 4; ++r) {
        if (eb[r] >= 0) {
            int off = atomicAdd(&h[eb[r]], 1);
            int slot = sstart[eb[r]] + off;
            ebuf[slot] = ep[r];
            sbk[slot] = (unsigned short)eb[r];
        }
    }
    __syncthreads();
#pragma unroll
    for (int r = 0; r < 4; ++r) {
        int i = tid + 1024 * r;
        if (i < cntE) {
            int bk = sbk[i];
            pairbuf[gbase[bk] + (i - sstart[bk])] = ebuf[i];
        }
    }
}

// ---------------------------------------------------------------------------
// Build CSR (proven, untouched): rows padded to multiples of 16 with sentinel
// index N_NODES; LDS-staged coalesced output.
// ---------------------------------------------------------------------------
__global__ __launch_bounds__(1024, 2) void k_build_csr(const int* __restrict__ cursor,
                                                       const int* __restrict__ pairbuf,
                                                       int* __restrict__ rowptr,
                                                       int* __restrict__ csr)
{
    __shared__ int cnt[256];
    __shared__ int scanv[256];
    __shared__ int ebuf[PAIR_CAP];
    __shared__ int obuf[CSR_CAP];
    int b = blockIdx.x;
    int base = b * CSR_CAP;
    int pbase = b * PAIR_CAP;
    int cntE = cursor[b];
    int tid = threadIdx.x;
    if (tid < 256) cnt[tid] = 0;
    __syncthreads();
    for (int i = tid; i < cntE; i += 1024) {
        int p = __builtin_nontemporal_load(&pairbuf[pbase + i]);
        ebuf[i] = p;
        atomicAdd(&cnt[(p >> 17) & 255], 1);
    }
    __syncthreads();
    int v = 0, vr = 0;
    if (tid < 256) { v = cnt[tid]; vr = (v + 15) & ~15; scanv[tid] = vr; }
    __syncthreads();
    for (int off = 1; off < 256; off <<= 1) {
        int t = (tid < 256 && tid >= off) ? scanv[tid - off] : 0;
        __syncthreads();
        if (tid < 256) scanv[tid] += t;
        __syncthreads();
    }
    int ex = 0;
    if (tid < 256) {
        ex = scanv[tid] - vr;              // exclusive scan of padded counts
        rowptr[b * RPW + tid] = (unsigned)((base + ex) >> 4) | ((unsigned)(vr >> 4) << 20);
        cnt[tid] = ex;
    }
    __syncthreads();
    int pt = scanv[255];                   // padded total (multiple of 16)
    for (int i = tid; i < pt; i += 1024) obuf[i] = N_NODES;
    __syncthreads();
    for (int i = tid; i < cntE; i += 1024) {
        int p = ebuf[i];
        int pos = atomicAdd(&cnt[(p >> 17) & 255], 1);
        obuf[pos] = p & 0x1FFFF;
    }
    __syncthreads();
    for (int i = tid * 4; i < pt; i += 4096) {
        intx4 vv = *(const intx4*)(obuf + i);
        *(intx4*)(csr + base + i) = vv;
    }
}

// ---------------------------------------------------------------------------
// transform1 via MFMA f16 (proven, untouched): t1 = half(x @ W1_nbr);
// r1 = x @ W1_root + b1. Also zeroes sentinel row N_NODES of t1.
// ---------------------------------------------------------------------------
__global__ __launch_bounds__(256) void k_transform1_mfma(
    const float* __restrict__ x,
    const float* __restrict__ W1n, const float* __restrict__ W1r,
    const float* __restrict__ b1,
    __half* __restrict__ t1, float* __restrict__ r1)
{
    if (blockIdx.x == 0 && threadIdx.x < 16)
        ((unsigned short*)t1)[N_NODES * 16 + threadIdx.x] = 0;
    int wave = threadIdx.x >> 6;
    int lane = threadIdx.x & 63;
    int tile = blockIdx.x * 4 + wave;
    int node0 = tile * 16;
    int m = lane & 15, quad = lane >> 4;
    int row = node0 + m;
    if (row >= N_NODES) row = N_NODES - 1;
    const float* xr = x + (size_t)row * IN_CH + quad * 8;

    float4v acc_n = {0.f, 0.f, 0.f, 0.f};
    float4v acc_r = {0.f, 0.f, 0.f, 0.f};
#pragma unroll
    for (int kc = 0; kc < 4; ++kc) {
        half8 a, bn, br;
        const float* xp = xr + kc * 32;
#pragma unroll
        for (int j = 0; j < 8; ++j) a[j] = (_Float16)xp[j];
        int kbase = kc * 32 + quad * 8;
#pragma unroll
        for (int j = 0; j < 8; ++j) {
            bn[j] = (_Float16)W1n[(kbase + j) * 16 + m];
            br[j] = (_Float16)W1r[(kbase + j) * 16 + m];
        }
        acc_n = __builtin_amdgcn_mfma_f32_16x16x32_f16(a, bn, acc_n, 0, 0, 0);
        acc_r = __builtin_amdgcn_mfma_f32_16x16x32_f16(a, br, acc_r, 0, 0, 0);
    }
    float bias = b1[m];
#pragma unroll
    for (int reg = 0; reg < 4; ++reg) {
        int node = node0 + quad * 4 + reg;
        if (node < N_NODES) {
            t1[node * 16 + m] = __float2half_rn(acc_n[reg]);
            r1[node * 16 + m] = acc_r[reg] + bias;
        }
    }
}

// ---------------------------------------------------------------------------
// Layer-1 gather FUSED with combine1: agg = gather(t1); h1 = f16(relu(r1+agg)).
// Merged-hh core (R8-proven). Also zeroes sentinel row of h1.
// ---------------------------------------------------------------------------
__global__ __launch_bounds__(256) void k_gather16_h1(
    const int* __restrict__ rowptr, const int* __restrict__ csr,
    const unsigned* __restrict__ t,
    const float* __restrict__ r1, __half* __restrict__ h1)
{
    if (blockIdx.x == 0 && threadIdx.x < 16)
        h1[(size_t)N_NODES * 16 + threadIdx.x] = __float2half_rn(0.f);
    int n = blockIdx.x * 32 + (threadIdx.x >> 3);
    int cp = threadIdx.x & 7;
    float rx, ry;
    gather16_core(rowptr, csr, t, n, cp, rx, ry);
    float2 rr = *(const float2*)(r1 + n * 16 + 2 * cp);
    float vx = rr.x + rx; vx = vx > 0.f ? vx : 0.f;
    float vy = rr.y + ry; vy = vy > 0.f ? vy : 0.f;
    ((__half2*)h1)[n * 8 + cp] = __floats2half2_rn(vx, vy);
}

// ---------------------------------------------------------------------------
// Layer-2 gather: agg_h1 stored f16 (halves agg bytes; values ~1e3 << f16 max).
// ---------------------------------------------------------------------------
__global__ __launch_bounds__(256) void k_gather16_aggh(
    const int* __restrict__ rowptr, const int* __restrict__ csr,
    const unsigned* __restrict__ t,
    __half* __restrict__ aggh)
{
    int n = blockIdx.x * 32 + (threadIdx.x >> 3);
    int cp = threadIdx.x & 7;
    float rx, ry;
    gather16_core(rowptr, csr, t, n, cp, rx, ry);
    ((__half2*)aggh)[n * 8 + cp] = __floats2half2_rn(rx, ry);
}

// ---------------------------------------------------------------------------
// 32-channel gather (R7-proven form, untouched): 8 lanes/node x dwordx2,
// XCD-partitioned halves, used for layer-3 (h2 table).
// ---------------------------------------------------------------------------
__global__ __launch_bounds__(256) void k_gather32f(
    const int* __restrict__ rowptr, const int* __restrict__ csr,
    const unsigned* __restrict__ t,
    float* __restrict__ aggA, float* __restrict__ aggB)
{
    int b = blockIdx.x;
    int half = (b >> 2) & 1;
    int tile = (b >> 3) * 4 + (b & 3);
    if (tile >= NTILE32) return;
    int n = tile * 32 + (threadIdx.x >> 3);
    int cp = threadIdx.x & 7;
    float* agg = half ? aggB : aggA;
    unsigned w = ((const unsigned*)rowptr)[(half * NBH + (n >> 8)) * RPW + (n & 255)];
    int j = (int)(w & 0xFFFFFu) << 4;
    int end = j + ((int)(w >> 20) << 4);
    const uint2* tb = (const uint2*)t + cp;    // row = 8 uint2
    floatx2 ac[4], bc[4];
#pragma unroll
    for (int i = 0; i < 4; ++i) { ac[i] = (floatx2){0.f, 0.f}; bc[i] = (floatx2){0.f, 0.f}; }
    if (j < end) {
        int sv[16] __attribute__((aligned(16)));
        ld16(csr + j, sv);
        j += 16;
        while (j < end) {
            int sw[16] __attribute__((aligned(16)));
            ld16(csr + j, sw);
            j += 16;
            acc16w(tb, sv, ac, bc);
#pragma unroll
            for (int k = 0; k < 16; ++k) sv[k] = sw[k];
        }
        acc16w(tb, sv, ac, bc);
    }
    float r0 = (ac[0].x + ac[1].x) + (ac[2].x + ac[3].x);
    float r1 = (ac[0].y + ac[1].y) + (ac[2].y + ac[3].y);
    float r2 = (bc[0].x + bc[1].x) + (bc[2].x + bc[3].x);
    float r3 = (bc[0].y + bc[1].y) + (bc[2].y + bc[3].y);
    float* dst = agg + n * 32 + cp * 4;
    __builtin_nontemporal_store(r0, dst);
    __builtin_nontemporal_store(r1, dst + 1);
    __builtin_nontemporal_store(r2, dst + 2);
    __builtin_nontemporal_store(r3, dst + 3);
}

// ---------------------------------------------------------------------------
// combine2: h2 = relu([h1 | aggh] @ [W2r; W2n] + b2), K=32 concat MFMA.
// A: quad<2 -> h1 f16 direct; quad>=2 -> aggh f16 direct. Zeroes sentinel row.
// ---------------------------------------------------------------------------
__global__ __launch_bounds__(256) void k_combine2_mfma(
    const __half* __restrict__ h1,
    const __half* __restrict__ aggh,
    const float* __restrict__ W2r, const float* __restrict__ W2n,
    const float* __restrict__ b2,
    __half* __restrict__ h2)
{
    if (blockIdx.x == 0 && threadIdx.x < 32)
        h2[(size_t)N_NODES * 32 + threadIdx.x] = __float2half_rn(0.f);
    int wave = threadIdx.x >> 6;
    int lane = threadIdx.x & 63;
    int tile = blockIdx.x * 4 + wave;
    if (tile >= NTILE) return;
    int node0 = tile * 16;
    int m = lane & 15, quad = lane >> 4;

    half8 bf[2];
#pragma unroll
    for (int g = 0; g < 2; ++g) {
#pragma unroll
        for (int j = 0; j < 8; ++j) {
            int k = quad * 8 + j;
            int c = g * 16 + m;
            float w = (k < 16) ? W2r[k * 32 + c] : W2n[(k - 16) * 32 + c];
            bf[g][j] = (_Float16)w;
        }
    }

    half8 a;
    if (quad < 2) {
        a = *(const half8*)(h1 + (node0 + m) * 16 + quad * 8);
    } else {
        a = *(const half8*)(aggh + (node0 + m) * 16 + (quad - 2) * 8);
    }

    float4v acc0 = {0,0,0,0}, acc1 = {0,0,0,0};
    acc0 = __builtin_amdgcn_mfma_f32_16x16x32_f16(a, bf[0], acc0, 0, 0, 0);
    acc1 = __builtin_amdgcn_mfma_f32_16x16x32_f16(a, bf[1], acc1, 0, 0, 0);

    float bias0 = b2[m], bias1 = b2[16 + m];
#pragma unroll
    for (int reg = 0; reg < 4; ++reg) {
        int node = node0 + quad * 4 + reg;
        float v0 = acc0[reg] + bias0; v0 = v0 > 0.f ? v0 : 0.f;
        float v1 = acc1[reg] + bias1; v1 = v1 > 0.f ? v1 : 0.f;
        h2[node * 32 + m]      = __float2half_rn(v0);
        h2[node * 32 + 16 + m] = __float2half_rn(v1);
    }
}

// ---------------------------------------------------------------------------
// combine3 FUSED with pool: h3 = relu([h2 | aggA+aggB] @ [W3r; W3n] + b3)
// computed per 64-node block into LDS, then run-length pooled per graph
// (batch sorted -> contiguous) with ~2-3 atomicAdds per channel per block.
// Eliminates the 12.8MB h3 buffer entirely.
// ---------------------------------------------------------------------------
__global__ __launch_bounds__(256) void k_combine3_pool(
    const __half* __restrict__ h2,
    const float* __restrict__ aggA, const float* __restrict__ aggB,
    const float* __restrict__ W3r, const float* __restrict__ W3n,
    const float* __restrict__ b3,
    const int* __restrict__ batch,
    float* __restrict__ pooled)
{
    __shared__ float h3s[64][33];
    __shared__ int gb[64];
    int tid = threadIdx.x;
    int base = blockIdx.x * 64;
    if (tid < 64) {
        int node = base + tid;
        gb[tid] = (node < N_NODES) ? batch[node] : -1;
    }
    int wave = tid >> 6;
    int lane = tid & 63;
    int tile = blockIdx.x * 4 + wave;
    int node0 = tile * 16;
    int m = lane & 15, quad = lane >> 4;

    if (tile < NTILE) {
        half8 bfl[2], bfh[2];
#pragma unroll
        for (int g = 0; g < 2; ++g) {
#pragma unroll
            for (int j = 0; j < 8; ++j) {
                int k = quad * 8 + j;
                int c = g * 16 + m;
                bfl[g][j] = (_Float16)W3r[k * 32 + c];
                bfh[g][j] = (_Float16)W3n[k * 32 + c];
            }
        }

        int idx = (node0 + m) * 32 + quad * 8;
        half8 al = *(const half8*)(h2 + idx);
        half8 ah;
#pragma unroll
        for (int j = 0; j < 8; ++j)
            ah[j] = (_Float16)(aggA[idx + j] + aggB[idx + j]);

        float4v acc0 = {0,0,0,0}, acc1 = {0,0,0,0};
        acc0 = __builtin_amdgcn_mfma_f32_16x16x32_f16(al, bfl[0], acc0, 0, 0, 0);
        acc0 = __builtin_amdgcn_mfma_f32_16x16x32_f16(ah, bfh[0], acc0, 0, 0, 0);
        acc1 = __builtin_amdgcn_mfma_f32_16x16x32_f16(al, bfl[1], acc1, 0, 0, 0);
        acc1 = __builtin_amdgcn_mfma_f32_16x16x32_f16(ah, bfh[1], acc1, 0, 0, 0);

        float bias0 = b3[m], bias1 = b3[16 + m];
#pragma unroll
        for (int reg = 0; reg < 4; ++reg) {
            int local = wave * 16 + quad * 4 + reg;
            float v0 = acc0[reg] + bias0; v0 = v0 > 0.f ? v0 : 0.f;
            float v1 = acc1[reg] + bias1; v1 = v1 > 0.f ? v1 : 0.f;
            h3s[local][m]      = v0;
            h3s[local][16 + m] = v1;
        }
    }
    __syncthreads();
    if (tid < 32) {
        int c = tid;
        int gprev = gb[0];
        if (gprev >= 0) {
            float run = 0.f;
            for (int i = 0; i < 64; ++i) {
                int g = gb[i];
                if (g < 0) break;
                if (g != gprev) {
                    atomicAdd(&pooled[gprev * 32 + c], run);
                    run = 0.f; gprev = g;
                }
                run += h3s[i][c];
            }
            atomicAdd(&pooled[gprev * 32 + c], run);
        }
    }
}

// ---------------------------------------------------------------------------
// Final linear: out[g][o] = pooled[g] @ Wlin[:,o] + blin[o].
// ---------------------------------------------------------------------------
__global__ __launch_bounds__(256) void k_final(
    const float* __restrict__ pooled,
    const float* __restrict__ Wlin, const float* __restrict__ blin,
    float* __restrict__ out)
{
    int t = blockIdx.x * 256 + threadIdx.x;
    if (t >= NUM_GRAPHS * 64) return;
    int g = t >> 6, o = t & 63;
    float a = blin[o];
    const float* pg = pooled + g * 32;
#pragma unroll
    for (int k = 0; k < 32; ++k) a += pg[k] * Wlin[k * 64 + o];
    out[t] = a;
}

static inline char* align16p(char* p) {
    return (char*)(((uintptr_t)p + 15) & ~(uintptr_t)15);
}

extern "C" void kernel_launch(void* const* d_in, const int* in_sizes, int n_in,
                              void* d_out, int out_size, void* d_ws, size_t ws_size,
                              hipStream_t stream) {
    const float* x     = (const float*)d_in[0];
    const int*   ei    = (const int*)d_in[1];
    const int*   batch = (const int*)d_in[2];
    const float* W1r   = (const float*)d_in[3];
    const float* W1n   = (const float*)d_in[4];
    const float* b1    = (const float*)d_in[5];
    const float* W2r   = (const float*)d_in[6];
    const float* W2n   = (const float*)d_in[7];
    const float* b2    = (const float*)d_in[8];
    const float* W3r   = (const float*)d_in[9];
    const float* W3n   = (const float*)d_in[10];
    const float* b3    = (const float*)d_in[11];
    const float* Wlin  = (const float*)d_in[12];
    const float* blin  = (const float*)d_in[13];
    float* out = (float*)d_out;

    // ---- workspace layout --------------------------------------------------
    // cursor 4K | pooled 128K | rowptr 0.8MB | csr 21.6MB |
    // pairbuf 14.4MB { t1 3.2 + r1 6.4 during layer1; agg3B 12.8 for layer3 } |
    // aggreg 12.8MB { aggh f16 3.2 for layer2; agg3A f32 12.8 for layer3 } |
    // h1 3.2 | h2 6.4.   total ~59.4 MB.
    char* p = (char*)d_ws;
    int*   cursor = (int*)p;               p += 1024 * 4;
    float* pooled = (float*)p;             p += (size_t)NUM_GRAPHS * 32 * 4;
    int*   rowptr = (int*)p;               p += (size_t)NB2 * RPW * 4;
    p = align16p(p);
    int*   csr    = (int*)p;               p += (size_t)NB2 * CSR_CAP * 4;
    p = align16p(p);
    int*   pairbuf= (int*)p;
    __half* t1    = (__half*)pairbuf;                                   // alias
    float*  r1    = (float*)((char*)pairbuf + (size_t)(N_NODES + 1) * 16 * 2);
    float*  agg3B = (float*)pairbuf;       // alias, live for layer-3 only
    p += (size_t)NB2 * PAIR_CAP * 4;
    p = align16p(p);
    float*  agg3A = (float*)p;             // 12.8MB region
    __half* aggh  = (__half*)p;            // alias: layer-2 f16 agg (3.2MB)
    p += (size_t)N_NODES * 32 * 4;
    __half* h1    = (__half*)p;            p += (size_t)(N_NODES + 1) * 16 * 2;
    __half* h2    = (__half*)align16p(p);

    hipMemsetAsync(cursor, 0, 1024 * 4, stream);
    hipMemsetAsync(pooled, 0, (size_t)NUM_GRAPHS * 32 * 4, stream);

    // Bucketed CSR build
    k_scatter_pairs<<<NBLK_BIN, 1024, 0, stream>>>(ei, cursor, pairbuf);
    k_build_csr    <<<NB2, 1024, 0, stream>>>(cursor, pairbuf, rowptr, csr);

    // Layer 1: transform-first; gather fused with combine1
    k_transform1_mfma<<<(NTILE + 3) / 4, 256, 0, stream>>>(x, W1n, W1r, b1, t1, r1);
    k_gather16_h1<<<NBLK_G16, 256, 0, stream>>>(rowptr, csr,
                    (const unsigned*)t1, r1, h1);

    // Layer 2: aggregate-first; f16 agg
    k_gather16_aggh<<<NBLK_G16, 256, 0, stream>>>(rowptr, csr,
                    (const unsigned*)h1, aggh);
    k_combine2_mfma<<<(NTILE + 3) / 4, 256, 0, stream>>>(
                    h1, aggh, W2r, W2n, b2, h2);

    // Layer 3: aggregate-first; combine fused with pool
    k_gather32f<<<NBLK_G32, 256, 0, stream>>>(rowptr, csr,
                    (const unsigned*)h2, agg3A, agg3B);
    k_combine3_pool<<<(NTILE + 3) / 4, 256, 0, stream>>>(
                    h2, agg3A, agg3B, W3r, W3n, b3, batch, pooled);

    // Final linear
    k_final<<<(NUM_GRAPHS * 64 + 255) / 256, 256, 0, stream>>>(
                    pooled, Wlin, blin, out);
}